// Round 8
// baseline (161.238 us; speedup 1.0000x reference)
//
#include <hip/hip_runtime.h>

#define SEQ   200
#define BATCH 1024
#define DIM   300
#define HID   600
#define VOCAB 100000

#define BW    4            // batches per wave (mlp)
#define JCH   12           // j-chunks across blockIdx.y (mlp)
#define JPER  (HID / JCH)  // 50 j per chunk

#define NPAIR 3750000u     // (VOCAB*75)/2 f32x8 pairs per table

#define PACKED_BYTES ((size_t)VOCAB * HID * 2)   // 120,000,000
#define HIDDEN_BYTES ((size_t)BATCH * HID * 4)   // 2,457,600

typedef float        f32x4 __attribute__((ext_vector_type(4)));
typedef unsigned int u32x2 __attribute__((ext_vector_type(2)));

// ---------- bf16 helpers ----------
__device__ __forceinline__ unsigned int f2bf(float f) {
  const unsigned int u = __float_as_uint(f);
  return (u + 0x7FFFu + ((u >> 16) & 1u)) >> 16;   // RNE
}

// ---------- Kernel 0: fuse+convert tables to packed bf16 [VOCAB][600] ----
// Pair-processing: each thread converts two adjacent f32x4 slots (32B read,
// 2x8B stores). Writes target packed[v*150 + t*75 + c]; when the pair
// straddles a 75-slot row boundary (c==74) the second store lands at the
// next row's column 0 (branch-free address select). 14.3 iters/thread.
__global__ __launch_bounds__(256) void convert_kernel(
    const float* __restrict__ lut,
    const float* __restrict__ slut,
    u32x2* __restrict__ packed) {
  const unsigned int stride = gridDim.x * 256u;
  for (unsigned int o = blockIdx.x * 256u + threadIdx.x; o < 2u * NPAIR;
       o += stride) {
    const unsigned int t = (o >= NPAIR) ? 1u : 0u;
    const unsigned int p = o - t * NPAIR;
    const float* __restrict__ tab = t ? slut : lut;
    const f32x4 f0 = __builtin_nontemporal_load((const f32x4*)tab + 2u * p);
    const f32x4 f1 = __builtin_nontemporal_load((const f32x4*)tab + 2u * p + 1u);
    u32x2 r0, r1;
    r0.x = f2bf(f0.x) | (f2bf(f0.y) << 16);
    r0.y = f2bf(f0.z) | (f2bf(f0.w) << 16);
    r1.x = f2bf(f1.x) | (f2bf(f1.y) << 16);
    r1.y = f2bf(f1.z) | (f2bf(f1.w) << 16);
    const unsigned int s0 = 2u * p;          // first f32x4 slot index
    const unsigned int v  = s0 / 75u;
    const unsigned int c  = s0 - v * 75u;    // 0..74
    const size_t base = (size_t)v * 150u + (size_t)t * 75u + c;
    packed[base] = r0;
    packed[(c == 74u) ? base + 76u : base + 1u] = r1;  // straddle -> row v+1, col 0
  }
}

// ---------- Kernel 1: dedup + fused bf16 row-gather ----------------------
// One block per column. 3 s-groups x 75 lanes (225 active): grp g covers
// ~67 sequence slots; slot = 16B bf16x8 slice of the 1200B packed row.
__global__ __launch_bounds__(256) void embed_bf16_kernel(
    const int* __restrict__ tokens,
    const ushort* __restrict__ packed,
    float* __restrict__ hidden) {
  const int b = blockIdx.x;
  const int tid = threadIdx.x;

  __shared__ int   toks[SEQ];
  __shared__ float keep[SEQ];
  __shared__ float accs[3][75][8];   // 7.2 KB

  for (int s = tid; s < SEQ; s += 256) toks[s] = tokens[s * BATCH + b];
  __syncthreads();

  for (int s = tid; s < SEQ; s += 256) {
    const int t = toks[s];
    float m = 1.f;
    for (int p = 0; p < s; ++p) {
      if (toks[p] == t) { m = 0.f; break; }
    }
    keep[s] = m;
  }
  __syncthreads();

  const int grp  = tid / 75;    // 0,1,2 active; tid 225..255 idle
  const int slot = tid % 75;
  if (grp < 3) {
    float acc[8] = {0.f, 0.f, 0.f, 0.f, 0.f, 0.f, 0.f, 0.f};
    const int s0 = grp * 67;
    const int s1 = (grp == 2) ? SEQ : s0 + 67;
#pragma unroll 4
    for (int s = s0; s < s1; ++s) {
      const float m = keep[s];
      const uint4 u = *(const uint4*)(packed + (size_t)toks[s] * HID + slot * 8);
      acc[0] += m * __uint_as_float(u.x << 16);
      acc[1] += m * __uint_as_float(u.x & 0xFFFF0000u);
      acc[2] += m * __uint_as_float(u.y << 16);
      acc[3] += m * __uint_as_float(u.y & 0xFFFF0000u);
      acc[4] += m * __uint_as_float(u.z << 16);
      acc[5] += m * __uint_as_float(u.z & 0xFFFF0000u);
      acc[6] += m * __uint_as_float(u.w << 16);
      acc[7] += m * __uint_as_float(u.w & 0xFFFF0000u);
    }
#pragma unroll
    for (int q = 0; q < 8; ++q) accs[grp][slot][q] = acc[q];
  }
  __syncthreads();

  if (tid < 75) {
    float4 o0, o1;
    o0.x = accs[0][tid][0] + accs[1][tid][0] + accs[2][tid][0];
    o0.y = accs[0][tid][1] + accs[1][tid][1] + accs[2][tid][1];
    o0.z = accs[0][tid][2] + accs[1][tid][2] + accs[2][tid][2];
    o0.w = accs[0][tid][3] + accs[1][tid][3] + accs[2][tid][3];
    o1.x = accs[0][tid][4] + accs[1][tid][4] + accs[2][tid][4];
    o1.y = accs[0][tid][5] + accs[1][tid][5] + accs[2][tid][5];
    o1.z = accs[0][tid][6] + accs[1][tid][6] + accs[2][tid][6];
    o1.w = accs[0][tid][7] + accs[1][tid][7] + accs[2][tid][7];
    float* hb = hidden + (size_t)b * HID + tid * 8;
    *(float4*)hb       = o0;
    *((float4*)hb + 1) = o1;
  }
}

// ---------- Kernel 2a: out[b] = b2 ---------------------------------------
__global__ __launch_bounds__(256) void out_init_kernel(
    float* __restrict__ out, const float* __restrict__ b2) {
  const int i = blockIdx.x * 256 + threadIdx.x;
  if (i < BATCH) out[i] = b2[0];
}

// ---------- Kernel 2b: MLP — 4 batches/wave, W1 reused 4x, DPP reduce ----
template <int CTRL>
__device__ __forceinline__ float dpp_add(float x) {
  const int y = __builtin_amdgcn_update_dpp(
      0, __float_as_int(x), CTRL, 0xf, 0xf, true);
  return x + __int_as_float(y);
}

__device__ __forceinline__ float wave_sum(float h) {
  h = dpp_add<0x111>(h);   // row_shr:1
  h = dpp_add<0x112>(h);   // row_shr:2
  h = dpp_add<0x114>(h);   // row_shr:4
  h = dpp_add<0x118>(h);   // row_shr:8
  h = dpp_add<0x142>(h);   // row_bcast:15
  h = dpp_add<0x143>(h);   // row_bcast:31  -> lane 63 holds full sum
  return h;
}

__global__ __launch_bounds__(256) void mlp_kernel(
    const float* __restrict__ hidden,
    const float* __restrict__ W1,
    const float* __restrict__ b1,
    const float* __restrict__ W2,
    float* __restrict__ out) {
  const int wave = threadIdx.x >> 6;
  const int lane = threadIdx.x & 63;
  const int b0   = (blockIdx.x * 4 + wave) * BW;
  const int j0   = blockIdx.y * JPER;

  // preload 4 hidden rows: k = lane + 64*i (600 = 64*9 + 24)
  float a[BW][10];
#pragma unroll
  for (int bb = 0; bb < BW; ++bb) {
    const float* __restrict__ hb = hidden + (size_t)(b0 + bb) * HID;
#pragma unroll
    for (int i = 0; i < 9; ++i) a[bb][i] = hb[lane + 64 * i];
    a[bb][9] = (lane < 24) ? hb[lane + 576] : 0.f;
  }

  float acc[BW] = {0.f, 0.f, 0.f, 0.f};

#pragma unroll 2
  for (int jj = 0; jj < JPER; ++jj) {
    const int j = j0 + jj;
    const float* __restrict__ wr = W1 + (size_t)j * HID;
    float d0 = 0.f, d1 = 0.f, d2 = 0.f, d3 = 0.f;
#pragma unroll
    for (int i = 0; i < 9; ++i) {
      const float w = wr[lane + 64 * i];
      d0 += a[0][i] * w;
      d1 += a[1][i] * w;
      d2 += a[2][i] * w;
      d3 += a[3][i] * w;
    }
    {
      const float w = (lane < 24) ? wr[lane + 576] : 0.f;
      d0 += a[0][9] * w;
      d1 += a[1][9] * w;
      d2 += a[2][9] * w;
      d3 += a[3][9] * w;
    }
    // 4 independent 6-step DPP chains (ILP hides DPP latency)
    d0 = wave_sum(d0); d1 = wave_sum(d1);
    d2 = wave_sum(d2); d3 = wave_sum(d3);
    // branch-free epilogue: only lane 63's acc is ever consumed
    const float b1j = b1[j];
    const float w2j = W2[j];
    acc[0] += fmaxf(d0 + b1j, 0.f) * w2j;
    acc[1] += fmaxf(d1 + b1j, 0.f) * w2j;
    acc[2] += fmaxf(d2 + b1j, 0.f) * w2j;
    acc[3] += fmaxf(d3 + b1j, 0.f) * w2j;
  }

  if (lane == 63) {
#pragma unroll
    for (int bb = 0; bb < BW; ++bb) atomicAdd(&out[b0 + bb], acc[bb]);
  }
}

extern "C" void kernel_launch(void* const* d_in, const int* in_sizes, int n_in,
                              void* d_out, int out_size, void* d_ws, size_t ws_size,
                              hipStream_t stream) {
  const int*   tokens = (const int*)  d_in[0];
  const float* lut    = (const float*)d_in[1];
  const float* slut   = (const float*)d_in[2];
  const float* W1     = (const float*)d_in[3];
  const float* b1     = (const float*)d_in[4];
  const float* W2     = (const float*)d_in[5];
  const float* b2     = (const float*)d_in[6];
  float* out = (float*)d_out;

  ushort* packed = (ushort*)d_ws;
  float*  hidden = (float*)((char*)d_ws + PACKED_BYTES);

  out_init_kernel<<<(BATCH + 255) / 256, 256, 0, stream>>>(out, b2);
  convert_kernel<<<2048, 256, 0, stream>>>(lut, slut, (u32x2*)packed);
  embed_bf16_kernel<<<BATCH, 256, 0, stream>>>(tokens, packed, hidden);
  mlp_kernel<<<dim3(BATCH / (4 * BW), JCH), 256, 0, stream>>>(
      hidden, W1, b1, W2, out);
}

// Round 9
// 130.600 us; speedup vs baseline: 1.2346x; 1.2346x over previous
//
#include <hip/hip_runtime.h>

#define SEQ   200
#define BATCH 1024
#define DIM   300
#define HID   600
#define VOCAB 100000

#define NQ     4             // s-chunks per column (embed)
#define SCHUNK (SEQ / NQ)    // 50

#define BW    4              // batches per wave (mlp)
#define JCH   12             // j-chunks across blockIdx.y (mlp)
#define JPER  (HID / JCH)    // 50 j per chunk

#define HIDDEN_ELEMS (BATCH * HID)               // 614400
#define HIDDEN_BYTES ((size_t)HIDDEN_ELEMS * 4)  // 2,457,600

// ---------- Kernel 1: dedup + fp32 gather, 4 s-chunks per column ---------
// Grid (1024 columns, 4 chunks) x 192 threads -> ~10 resident blocks/CU
// (vs 4 with one block/column). Lanes 0..149 = (table, float4-slot); each
// gathers its chunk's 50 rows. Partial sums -> hid4[q][b][600].
__global__ __launch_bounds__(192) void embed_part_kernel(
    const int* __restrict__ tokens,
    const float* __restrict__ lut,
    const float* __restrict__ slut,
    float* __restrict__ hid4) {
  const int b   = blockIdx.x;
  const int q   = blockIdx.y;
  const int tid = threadIdx.x;

  __shared__ int   toks[SEQ];
  __shared__ float keep[SCHUNK];

  for (int s = tid; s < SEQ; s += 192) toks[s] = tokens[s * BATCH + b];
  __syncthreads();

  const int s0 = q * SCHUNK;
  if (tid < SCHUNK) {
    const int s = s0 + tid;
    const int t = toks[s];
    float m = 1.f;
    for (int p = 0; p < s; ++p) {        // full-prefix scan: dedup is global
      if (toks[p] == t) { m = 0.f; break; }
    }
    keep[tid] = m;
  }
  __syncthreads();

  const int tab_i = tid / 75;            // 0 -> lut, 1 -> slut, 2 -> idle
  const int slot  = tid % 75;            // float4 slice of the 300-float row
  if (tab_i < 2) {
    const float* __restrict__ tab = tab_i ? slut : lut;
    float4 a = make_float4(0.f, 0.f, 0.f, 0.f);
#pragma unroll 5
    for (int i = 0; i < SCHUNK; ++i) {
      const float  m = keep[i];          // 0/1, branch-free
      const float4 v = ((const float4*)(tab + (size_t)toks[s0 + i] * DIM))[slot];
      a.x += m * v.x; a.y += m * v.y; a.z += m * v.z; a.w += m * v.w;
    }
    float* dst = hid4 + ((size_t)q * BATCH + b) * HID + tab_i * DIM;
    ((float4*)dst)[slot] = a;
  }
}

// ---------- Kernel 1b: hidden = sum of 4 partials ------------------------
__global__ __launch_bounds__(256) void combine_kernel(
    const float* __restrict__ hid4, float* __restrict__ hidden) {
  const int i = blockIdx.x * 256 + threadIdx.x;   // float4 index
  const int n4 = HIDDEN_ELEMS / 4;                // 153600
  if (i < n4) {
    const float4* p = (const float4*)hid4;
    const float4 a = p[i];
    const float4 b = p[i + n4];
    const float4 c = p[i + 2 * n4];
    const float4 d = p[i + 3 * n4];
    float4 s;
    s.x = (a.x + b.x) + (c.x + d.x);
    s.y = (a.y + b.y) + (c.y + d.y);
    s.z = (a.z + b.z) + (c.z + d.z);
    s.w = (a.w + b.w) + (c.w + d.w);
    ((float4*)hidden)[i] = s;
  }
}

// ---------- Kernel 2a: out[b] = b2 ---------------------------------------
__global__ __launch_bounds__(256) void out_init_kernel(
    float* __restrict__ out, const float* __restrict__ b2) {
  const int i = blockIdx.x * 256 + threadIdx.x;
  if (i < BATCH) out[i] = b2[0];
}

// ---------- Kernel 2b: MLP — 4 batches/wave, W1 reused 4x, DPP reduce ----
template <int CTRL>
__device__ __forceinline__ float dpp_add(float x) {
  const int y = __builtin_amdgcn_update_dpp(
      0, __float_as_int(x), CTRL, 0xf, 0xf, true);
  return x + __int_as_float(y);
}

__device__ __forceinline__ float wave_sum(float h) {
  h = dpp_add<0x111>(h);   // row_shr:1
  h = dpp_add<0x112>(h);   // row_shr:2
  h = dpp_add<0x114>(h);   // row_shr:4
  h = dpp_add<0x118>(h);   // row_shr:8
  h = dpp_add<0x142>(h);   // row_bcast:15
  h = dpp_add<0x143>(h);   // row_bcast:31  -> lane 63 holds full sum
  return h;
}

__global__ __launch_bounds__(256) void mlp_kernel(
    const float* __restrict__ hidden,
    const float* __restrict__ W1,
    const float* __restrict__ b1,
    const float* __restrict__ W2,
    float* __restrict__ out) {
  const int wave = threadIdx.x >> 6;
  const int lane = threadIdx.x & 63;
  const int b0   = (blockIdx.x * 4 + wave) * BW;
  const int j0   = blockIdx.y * JPER;

  // preload 4 hidden rows: k = lane + 64*i (600 = 64*9 + 24)
  float a[BW][10];
#pragma unroll
  for (int bb = 0; bb < BW; ++bb) {
    const float* __restrict__ hb = hidden + (size_t)(b0 + bb) * HID;
#pragma unroll
    for (int i = 0; i < 9; ++i) a[bb][i] = hb[lane + 64 * i];
    a[bb][9] = (lane < 24) ? hb[lane + 576] : 0.f;
  }

  float acc[BW] = {0.f, 0.f, 0.f, 0.f};

#pragma unroll 2
  for (int jj = 0; jj < JPER; ++jj) {
    const int j = j0 + jj;
    const float* __restrict__ wr = W1 + (size_t)j * HID;
    float d0 = 0.f, d1 = 0.f, d2 = 0.f, d3 = 0.f;
#pragma unroll
    for (int i = 0; i < 9; ++i) {
      const float w = wr[lane + 64 * i];
      d0 += a[0][i] * w;
      d1 += a[1][i] * w;
      d2 += a[2][i] * w;
      d3 += a[3][i] * w;
    }
    {
      const float w = (lane < 24) ? wr[lane + 576] : 0.f;
      d0 += a[0][9] * w;
      d1 += a[1][9] * w;
      d2 += a[2][9] * w;
      d3 += a[3][9] * w;
    }
    // 4 independent 6-step DPP chains (ILP hides DPP latency)
    d0 = wave_sum(d0); d1 = wave_sum(d1);
    d2 = wave_sum(d2); d3 = wave_sum(d3);
    // branch-free epilogue: only lane 63's acc is ever consumed
    const float b1j = b1[j];
    const float w2j = W2[j];
    acc[0] += fmaxf(d0 + b1j, 0.f) * w2j;
    acc[1] += fmaxf(d1 + b1j, 0.f) * w2j;
    acc[2] += fmaxf(d2 + b1j, 0.f) * w2j;
    acc[3] += fmaxf(d3 + b1j, 0.f) * w2j;
  }

  if (lane == 63) {
#pragma unroll
    for (int bb = 0; bb < BW; ++bb) atomicAdd(&out[b0 + bb], acc[bb]);
  }
}

extern "C" void kernel_launch(void* const* d_in, const int* in_sizes, int n_in,
                              void* d_out, int out_size, void* d_ws, size_t ws_size,
                              hipStream_t stream) {
  const int*   tokens = (const int*)  d_in[0];
  const float* lut    = (const float*)d_in[1];
  const float* slut   = (const float*)d_in[2];
  const float* W1     = (const float*)d_in[3];
  const float* b1     = (const float*)d_in[4];
  const float* W2     = (const float*)d_in[5];
  const float* b2     = (const float*)d_in[6];
  float* out = (float*)d_out;

  float* hid4   = (float*)d_ws;                                  // 4 x 2.4 MB
  float* hidden = (float*)((char*)d_ws + (size_t)NQ * HIDDEN_BYTES);

  out_init_kernel<<<(BATCH + 255) / 256, 256, 0, stream>>>(out, b2);
  embed_part_kernel<<<dim3(BATCH, NQ), 192, 0, stream>>>(
      tokens, lut, slut, hid4);
  combine_kernel<<<(HIDDEN_ELEMS / 4 + 255) / 256, 256, 0, stream>>>(
      hid4, hidden);
  mlp_kernel<<<dim3(BATCH / (4 * BW), JCH), 256, 0, stream>>>(
      hidden, W1, b1, W2, out);
}